// Round 1
// baseline (202.318 us; speedup 1.0000x reference)
//
#include <hip/hip_runtime.h>
#include <hip/hip_bf16.h>
#include <hip/hip_fp16.h>

// GAT layer on MI355X (gfx950).
//   x: (N=50000, K=256) fp32, W: (K=256, F=64) fp32, a: (1, 128) fp32
//   edge_index: (2, E=1600000) int (src row 0, dst row 1)
// out = elu( segsum_src(e * h[dst]) / segsum_src(e) ),
//   e = exp(-leakyrelu(s_src[src]+s_dst[dst], 0.2)), h = x@W
//
// Round 11: the fused gemm+bin kernel and bsort were latency-bound at
// ~20% occupancy (782 / 782 blocks = 12 waves/CU). Doubled block counts
// everywhere: gemm 64 rows/block (782 blocks), BIN_CHUNK 2048 (782
// blocks), buckets narrowed 64->32 srcs (NBU 1563 bsort blocks,
// BUCKET_CAP 2048). Pair packing now (s&31)<<16 | dst.

#define ALPHA 0.2f
#define KDIM 256
#define FDIM 64
#define BIN_CHUNK 2048
#define BUCKET_CAP 2048    // 32-src bucket: mean ~1024 edges; ~32 sigma slack
#define HIST_SZ 2048       // >= NBU = ceil(50000/32) = 1563

typedef __bf16 bf16x8 __attribute__((ext_vector_type(8)));
typedef float f32x4 __attribute__((ext_vector_type(4)));
typedef unsigned int u32;
typedef unsigned short u16;

// ---------------------------------------------------------------------------
// Kernel 0: w_t[n][k] = bf16(W[k][n]) (32 KB, L1-resident) + zero bcur.
// ---------------------------------------------------------------------------
__global__ __launch_bounds__(256) void gat_wt_kernel(
    const float* __restrict__ W, __hip_bfloat16* __restrict__ w_t,
    int* __restrict__ bcur)
{
    const int t = blockIdx.x * 256 + threadIdx.x;
    if (t < KDIM * FDIM) {
        const int k = t >> 6;
        const int n = t & 63;
        w_t[n * KDIM + k] = __float2bfloat16(W[t]);
    }
    if (t < HIST_SZ) bcur[t] = 0;
}

// ---------------------------------------------------------------------------
// Kernel 1 (fused): blocks [0,NBLK) = bin; blocks [NBLK, NBLK+GB) = gemm.
//
// bin: local hist over 32-src buckets, one reservation atomic per
//      (block,bucket) on bcur, scatter packed (srclo<<16)|dst into arena.
// gemm: h = bf16(x @ W) via mfma_f32_16x16x32_bf16, scores fp32;
//       1 row-tile (16 rows) per wave, 64 rows/block.
// ---------------------------------------------------------------------------
__global__ __launch_bounds__(256) void gat_gemm_bin_kernel(
    const float* __restrict__ x, const __hip_bfloat16* __restrict__ w_tp,
    const float* __restrict__ a, __hip_bfloat16* __restrict__ h_bf,
    float* __restrict__ s_src, float* __restrict__ s_dst,
    const int* __restrict__ srcA, const int* __restrict__ dstA,
    int* __restrict__ bcur, u32* __restrict__ pair,
    int N, int E, int NBU, int NBLK)
{
    __shared__ int hist[HIST_SZ];
    __shared__ int lcur[HIST_SZ];

    const int t = threadIdx.x;

    if ((int)blockIdx.x < NBLK) {
        // ---------------- bin path ----------------
        for (int j = t; j < HIST_SZ; j += 256) hist[j] = 0;
        __syncthreads();
        const int base = blockIdx.x * BIN_CHUNK;
        const int cnt = min(BIN_CHUNK, E - base);
        for (int i = t; i < cnt; i += 256)
            atomicAdd(&hist[srcA[base + i] >> 5], 1);
        __syncthreads();
        for (int j = t; j < NBU; j += 256) {
            const int v = hist[j];
            lcur[j] = v ? (j * BUCKET_CAP + atomicAdd(&bcur[j], v)) : 0;
        }
        __syncthreads();
        for (int i = t; i < cnt; i += 256) {
            const int s = srcA[base + i];
            const int d = dstA[base + i];
            const int pos = atomicAdd(&lcur[s >> 5], 1);
            pair[pos] = ((u32)(s & 31) << 16) | (u32)d;   // d < 65536
        }
        return;
    }

    // ---------------- gemm path ----------------
    const int gb = (int)blockIdx.x - NBLK;
    const int lane = t & 63;
    const int wv = t >> 6;
    const int m0 = gb * 64 + wv * 16;   // this wave: rows m0..m0+15
    const int c = lane & 15;
    const int q = lane >> 4;

    const int r0 = m0 + c;
    const float* xp0 = x + (long)(r0 < N ? r0 : N - 1) * KDIM;
    const __bf16* wt = (const __bf16*)w_tp;

    f32x4 acc[4];
#pragma unroll
    for (int ct = 0; ct < 4; ++ct) acc[ct] = (f32x4){0.f, 0.f, 0.f, 0.f};

#pragma unroll 2
    for (int kc = 0; kc < 8; ++kc) {
        const int k0 = kc * 32 + q * 8;
        const float4 xa0 = *(const float4*)(xp0 + k0);
        const float4 xb0 = *(const float4*)(xp0 + k0 + 4);
        bf16x8 af0;
        af0[0] = (__bf16)xa0.x; af0[1] = (__bf16)xa0.y;
        af0[2] = (__bf16)xa0.z; af0[3] = (__bf16)xa0.w;
        af0[4] = (__bf16)xb0.x; af0[5] = (__bf16)xb0.y;
        af0[6] = (__bf16)xb0.z; af0[7] = (__bf16)xb0.w;
#pragma unroll
        for (int ct = 0; ct < 4; ++ct) {
            const bf16x8 bf = *(const bf16x8*)(wt + (ct * 16 + c) * KDIM + k0);
            acc[ct] = __builtin_amdgcn_mfma_f32_16x16x32_bf16(af0, bf, acc[ct], 0, 0, 0);
        }
    }

    float a1c[4], a2c[4];
#pragma unroll
    for (int ct = 0; ct < 4; ++ct) {
        a1c[ct] = a[ct * 16 + c];
        a2c[ct] = a[FDIM + ct * 16 + c];
    }

    float s1r[4], s2r[4];
#pragma unroll
    for (int reg = 0; reg < 4; ++reg) {
        float s1 = 0.f, s2 = 0.f;
#pragma unroll
        for (int ct = 0; ct < 4; ++ct) {
            s1 += acc[ct][reg] * a1c[ct];
            s2 += acc[ct][reg] * a2c[ct];
        }
        s1r[reg] = s1; s2r[reg] = s2;
    }
#pragma unroll
    for (int off = 1; off < 16; off <<= 1) {
#pragma unroll
        for (int reg = 0; reg < 4; ++reg) {
            s1r[reg] += __shfl_xor(s1r[reg], off);
            s2r[reg] += __shfl_xor(s2r[reg], off);
        }
    }
#pragma unroll
    for (int reg = 0; reg < 4; ++reg) {
        const int row = m0 + q * 4 + reg;
        if (row < N) {
#pragma unroll
            for (int ct = 0; ct < 4; ++ct)
                h_bf[(long)row * FDIM + ct * 16 + c] = __float2bfloat16(acc[ct][reg]);
            if (c == 0) { s_src[row] = s1r[reg]; s_dst[row] = s2r[reg]; }
        }
    }
}

// ---------------------------------------------------------------------------
// Kernel 2: per-bucket LDS counting sort + weight pack. One block per 32-src
// bucket (8 KB LDS chunk). Count from bcur[b]. Emits per-node [nstart,nend)
// and sorted_pk = dst | f16(wgt)<<16 in the bucket's arena slot.
// ---------------------------------------------------------------------------
__global__ __launch_bounds__(256) void gat_bsort_kernel(
    const u32* __restrict__ pair, const int* __restrict__ bcur,
    const float* __restrict__ s_src, const float* __restrict__ s_dst,
    int* __restrict__ nstart, int* __restrict__ nend,
    u32* __restrict__ sorted_pk, int N)
{
    __shared__ u32 chunk[BUCKET_CAP];   // 8 KB
    __shared__ int cur[32];
    __shared__ float ssl[32];

    const int b = blockIdx.x;
    const int t = threadIdx.x;
    const int s0 = b << 5;
    const int abase = b * BUCKET_CAP;
    const int n = min(bcur[b], BUCKET_CAP);

    if (t < 32) {
        cur[t] = 0;
        ssl[t] = (s0 + t < N) ? s_src[s0 + t] : 0.f;
    }
    __syncthreads();
    for (int i = t; i < n; i += 256) {
        const u32 p = pair[abase + i];
        chunk[i] = p;
        atomicAdd(&cur[p >> 16], 1);
    }
    __syncthreads();
    if (t < 32) {   // lanes 0..31 of wave 0: exclusive scan of 32 counts
        const int v = cur[t];
        int incl = v;
#pragma unroll
        for (int off = 1; off < 32; off <<= 1) {
            const int nv = __shfl_up(incl, off);
            if (t >= off) incl += nv;
        }
        const int excl = incl - v;
        if (s0 + t < N) {
            nstart[s0 + t] = abase + excl;
            nend[s0 + t] = abase + excl + v;
        }
        cur[t] = excl;
    }
    __syncthreads();
    for (int i = t; i < n; i += 256) {
        const u32 p = chunk[i];
        const int sl = p >> 16;
        const int d = (int)(p & 0xFFFFu);
        const int slot = atomicAdd(&cur[sl], 1);
        const float sc = ssl[sl] + s_dst[d];
        const float lr = sc > 0.f ? sc : ALPHA * sc;
        const float wgt = __expf(-lr);
        const u32 wh = (u32)__half_as_ushort(__float2half(wgt));
        sorted_pk[abase + slot] = (u32)d | (wh << 16);
    }
}

// ---------------------------------------------------------------------------
// Kernel 3: segmented reduction over bf16 h. One wave per node; 8 edge slots
// x 8 feature octets; 2 independent edge streams per lane.
// ---------------------------------------------------------------------------
__global__ __launch_bounds__(256) void gat_gather_kernel(
    const int* __restrict__ nstart, const int* __restrict__ nend,
    const u32* __restrict__ sorted_pk,
    const __hip_bfloat16* __restrict__ h_bf, float* __restrict__ out, int N)
{
    const int node = blockIdx.x * 4 + (threadIdx.x >> 6);
    if (node >= N) return;
    const int lane = threadIdx.x & 63;
    const int q = lane >> 3;   // edge slot 0..7
    const int c = lane & 7;    // feature octet 0..7

    const int start = nstart[node];
    const int end = nend[node];
    const __bf16* hb = (const __bf16*)h_bf;

    float acc0[8], acc1[8];
#pragma unroll
    for (int j = 0; j < 8; ++j) { acc0[j] = 0.f; acc1[j] = 0.f; }
    float wsum0 = 0.f, wsum1 = 0.f;

    int e = start + q;
    for (; e + 8 < end; e += 16) {
        const u32 p0 = sorted_pk[e];
        const u32 p1 = sorted_pk[e + 8];
        const int d0 = (int)(p0 & 0xFFFFu);
        const int d1 = (int)(p1 & 0xFFFFu);
        const bf16x8 hv0 = *(const bf16x8*)(hb + (long)d0 * FDIM + 8 * c);
        const bf16x8 hv1 = *(const bf16x8*)(hb + (long)d1 * FDIM + 8 * c);
        const float w0 = __half2float(__ushort_as_half((u16)(p0 >> 16)));
        const float w1 = __half2float(__ushort_as_half((u16)(p1 >> 16)));
#pragma unroll
        for (int j = 0; j < 8; ++j) {
            acc0[j] += w0 * (float)hv0[j];
            acc1[j] += w1 * (float)hv1[j];
        }
        wsum0 += w0;
        wsum1 += w1;
    }
    if (e < end) {
        const u32 p0 = sorted_pk[e];
        const int d0 = (int)(p0 & 0xFFFFu);
        const bf16x8 hv0 = *(const bf16x8*)(hb + (long)d0 * FDIM + 8 * c);
        const float w0 = __half2float(__ushort_as_half((u16)(p0 >> 16)));
#pragma unroll
        for (int j = 0; j < 8; ++j) acc0[j] += w0 * (float)hv0[j];
        wsum0 += w0;
    }

    float acc[8];
#pragma unroll
    for (int j = 0; j < 8; ++j) acc[j] = acc0[j] + acc1[j];
    float wsum = wsum0 + wsum1;

#pragma unroll
    for (int off = 8; off < 64; off <<= 1) {
#pragma unroll
        for (int j = 0; j < 8; ++j) acc[j] += __shfl_xor(acc[j], off);
        wsum += __shfl_xor(wsum, off);
    }

    if (q == 0) {
        const float inv = 1.0f / wsum;
        float o[8];
#pragma unroll
        for (int j = 0; j < 8; ++j) {
            const float v = acc[j] * inv;
            o[j] = v > 0.f ? v : expm1f(v);
        }
        float* op = &out[(long)node * FDIM + 8 * c];
        *(float4*)op = make_float4(o[0], o[1], o[2], o[3]);
        *(float4*)(op + 4) = make_float4(o[4], o[5], o[6], o[7]);
    }
}

extern "C" void kernel_launch(void* const* d_in, const int* in_sizes, int n_in,
                              void* d_out, int out_size, void* d_ws, size_t ws_size,
                              hipStream_t stream) {
    const float* x = (const float*)d_in[0];
    const float* W = (const float*)d_in[1];
    const float* a = (const float*)d_in[2];
    const int* ei  = (const int*)d_in[3];

    const int N = in_sizes[0] / KDIM;       // 50000
    const int E = in_sizes[3] / 2;          // 1600000
    const int NBU = (N + 31) >> 5;          // 1563 buckets of 32 srcs
    const int NBLK = (E + BIN_CHUNK - 1) / BIN_CHUNK;  // 782 bin chunks
    const int GB = (N + 63) / 64;                      // 782 gemm blocks
    const int* srcA = ei;
    const int* dstA = ei + E;

    // workspace layout (all regions 16B aligned; ~33 MB)
    __hip_bfloat16* h_bf = (__hip_bfloat16*)d_ws;          // N*64 bf16
    __hip_bfloat16* w_t  = h_bf + (size_t)N * FDIM;        // 64*256 bf16
    float* s_src = (float*)(w_t + KDIM * FDIM);            // N
    float* s_dst = s_src + N;                              // N
    int* nstart  = (int*)(s_dst + N);                      // N
    int* nend    = nstart + N;                             // N
    int* bcur    = nend + N;                               // HIST_SZ (zeroed by wt)
    u32* pair    = (u32*)(bcur + HIST_SZ);                 // NBU*CAP arena
    u32* sorted_pk = pair + (size_t)NBU * BUCKET_CAP;      // NBU*CAP arena
    float* out   = (float*)d_out;

    gat_wt_kernel<<<dim3((KDIM * FDIM + 255) / 256), dim3(256), 0, stream>>>(
        W, w_t, bcur);

    gat_gemm_bin_kernel<<<dim3(NBLK + GB), dim3(256), 0, stream>>>(
        x, w_t, a, h_bf, s_src, s_dst, srcA, dstA, bcur, pair, N, E, NBU, NBLK);

    gat_bsort_kernel<<<dim3(NBU), dim3(256), 0, stream>>>(
        pair, bcur, s_src, s_dst, nstart, nend, sorted_pk, N);

    gat_gather_kernel<<<dim3((N + 3) / 4), dim3(256), 0, stream>>>(
        nstart, nend, sorted_pk, h_bf, out, N);
}

// Round 2
// 169.975 us; speedup vs baseline: 1.1903x; 1.1903x over previous
//
#include <hip/hip_runtime.h>
#include <hip/hip_bf16.h>
#include <hip/hip_fp16.h>

// GAT layer on MI355X (gfx950).
//   x: (N=50000, K=256) fp32, W: (K=256, F=64) fp32, a: (1, 128) fp32
//   edge_index: (2, E=1600000) int (src row 0, dst row 1)
// out = elu( segsum_src(e * h[dst]) / segsum_src(e) ),
//   e = exp(-leakyrelu(s_src[src]+s_dst[dst], 0.2)), h = x@W
//
// Round 12: round-11 (more blocks / narrower buckets) regressed: occupancy
// 20->42% but WRITE_SIZE +19MB (scatter fragmentation) and 3x global bcur
// atomics -> 45->70us. Reverted K1 to round-10 exactly (BIN_CHUNK 4096,
// 64-src buckets, CAP 4096, 2 row-tiles/wave). New: bsort+gather fused into
// ONE kernel (one block per bucket, 512 thr): counting sort stays in LDS,
// gather reads edge lists from LDS -> kills the sorted_pk/nstart/nend HBM
// round-trip and one launch.

#define ALPHA 0.2f
#define KDIM 256
#define FDIM 64
#define BIN_CHUNK 4096
#define BUCKET_CAP 4096    // 64-src bucket: mean ~2046 edges; >40 sigma slack

typedef __bf16 bf16x8 __attribute__((ext_vector_type(8)));
typedef float f32x4 __attribute__((ext_vector_type(4)));
typedef unsigned int u32;
typedef unsigned short u16;

// ---------------------------------------------------------------------------
// Kernel 0: w_t[n][k] = bf16(W[k][n]) (32 KB, L1-resident) + zero bcur.
// ---------------------------------------------------------------------------
__global__ __launch_bounds__(256) void gat_wt_kernel(
    const float* __restrict__ W, __hip_bfloat16* __restrict__ w_t,
    int* __restrict__ bcur)
{
    const int t = blockIdx.x * 256 + threadIdx.x;
    if (t < KDIM * FDIM) {
        const int k = t >> 6;
        const int n = t & 63;
        w_t[n * KDIM + k] = __float2bfloat16(W[t]);
    }
    if (t < 1024) bcur[t] = 0;
}

// ---------------------------------------------------------------------------
// Kernel 1 (fused): blocks [0,NBLK) = bin; blocks [NBLK, NBLK+GB) = gemm.
// (round-10 configuration, verified 45us / 176us total)
// ---------------------------------------------------------------------------
__global__ __launch_bounds__(256) void gat_gemm_bin_kernel(
    const float* __restrict__ x, const __hip_bfloat16* __restrict__ w_tp,
    const float* __restrict__ a, __hip_bfloat16* __restrict__ h_bf,
    float* __restrict__ s_src, float* __restrict__ s_dst,
    const int* __restrict__ srcA, const int* __restrict__ dstA,
    int* __restrict__ bcur, u32* __restrict__ pair,
    int N, int E, int NBU, int NBLK)
{
    __shared__ int hist[1024];
    __shared__ int lcur[1024];

    const int t = threadIdx.x;

    if ((int)blockIdx.x < NBLK) {
        // ---------------- bin path ----------------
        for (int j = t; j < 1024; j += 256) hist[j] = 0;
        __syncthreads();
        const int base = blockIdx.x * BIN_CHUNK;
        const int cnt = min(BIN_CHUNK, E - base);
        for (int i = t; i < cnt; i += 256)
            atomicAdd(&hist[srcA[base + i] >> 6], 1);
        __syncthreads();
        for (int j = t; j < NBU; j += 256) {
            const int v = hist[j];
            lcur[j] = v ? (j * BUCKET_CAP + atomicAdd(&bcur[j], v)) : 0;
        }
        __syncthreads();
        for (int i = t; i < cnt; i += 256) {
            const int s = srcA[base + i];
            const int d = dstA[base + i];
            const int pos = atomicAdd(&lcur[s >> 6], 1);
            pair[pos] = ((u32)(s & 63) << 16) | (u32)d;   // d < 65536
        }
        return;
    }

    // ---------------- gemm path ----------------
    const int gb = (int)blockIdx.x - NBLK;
    const int lane = t & 63;
    const int wv = t >> 6;
    const int m0 = gb * 128 + wv * 32;   // this wave: rows m0..m0+31
    const int c = lane & 15;
    const int q = lane >> 4;

    const int r0 = m0 + c;
    const int r1 = m0 + 16 + c;
    const float* xp0 = x + (long)(r0 < N ? r0 : N - 1) * KDIM;
    const float* xp1 = x + (long)(r1 < N ? r1 : N - 1) * KDIM;
    const __bf16* wt = (const __bf16*)w_tp;

    f32x4 acc[2][4];
#pragma unroll
    for (int rt = 0; rt < 2; ++rt)
#pragma unroll
        for (int ct = 0; ct < 4; ++ct) acc[rt][ct] = (f32x4){0.f, 0.f, 0.f, 0.f};

#pragma unroll 2
    for (int kc = 0; kc < 8; ++kc) {
        const int k0 = kc * 32 + q * 8;
        const float4 xa0 = *(const float4*)(xp0 + k0);
        const float4 xb0 = *(const float4*)(xp0 + k0 + 4);
        const float4 xa1 = *(const float4*)(xp1 + k0);
        const float4 xb1 = *(const float4*)(xp1 + k0 + 4);
        bf16x8 af0, af1;
        af0[0] = (__bf16)xa0.x; af0[1] = (__bf16)xa0.y;
        af0[2] = (__bf16)xa0.z; af0[3] = (__bf16)xa0.w;
        af0[4] = (__bf16)xb0.x; af0[5] = (__bf16)xb0.y;
        af0[6] = (__bf16)xb0.z; af0[7] = (__bf16)xb0.w;
        af1[0] = (__bf16)xa1.x; af1[1] = (__bf16)xa1.y;
        af1[2] = (__bf16)xa1.z; af1[3] = (__bf16)xa1.w;
        af1[4] = (__bf16)xb1.x; af1[5] = (__bf16)xb1.y;
        af1[6] = (__bf16)xb1.z; af1[7] = (__bf16)xb1.w;
#pragma unroll
        for (int ct = 0; ct < 4; ++ct) {
            const bf16x8 bf = *(const bf16x8*)(wt + (ct * 16 + c) * KDIM + k0);
            acc[0][ct] = __builtin_amdgcn_mfma_f32_16x16x32_bf16(af0, bf, acc[0][ct], 0, 0, 0);
            acc[1][ct] = __builtin_amdgcn_mfma_f32_16x16x32_bf16(af1, bf, acc[1][ct], 0, 0, 0);
        }
    }

    float a1c[4], a2c[4];
#pragma unroll
    for (int ct = 0; ct < 4; ++ct) {
        a1c[ct] = a[ct * 16 + c];
        a2c[ct] = a[FDIM + ct * 16 + c];
    }

#pragma unroll
    for (int rt = 0; rt < 2; ++rt) {
        const int mb = m0 + rt * 16;
        float s1r[4], s2r[4];
#pragma unroll
        for (int reg = 0; reg < 4; ++reg) {
            float s1 = 0.f, s2 = 0.f;
#pragma unroll
            for (int ct = 0; ct < 4; ++ct) {
                s1 += acc[rt][ct][reg] * a1c[ct];
                s2 += acc[rt][ct][reg] * a2c[ct];
            }
            s1r[reg] = s1; s2r[reg] = s2;
        }
#pragma unroll
        for (int off = 1; off < 16; off <<= 1) {
#pragma unroll
            for (int reg = 0; reg < 4; ++reg) {
                s1r[reg] += __shfl_xor(s1r[reg], off);
                s2r[reg] += __shfl_xor(s2r[reg], off);
            }
        }
#pragma unroll
        for (int reg = 0; reg < 4; ++reg) {
            const int row = mb + q * 4 + reg;
            if (row < N) {
#pragma unroll
                for (int ct = 0; ct < 4; ++ct)
                    h_bf[(long)row * FDIM + ct * 16 + c] = __float2bfloat16(acc[rt][ct][reg]);
                if (c == 0) { s_src[row] = s1r[reg]; s_dst[row] = s2r[reg]; }
            }
        }
    }
}

// ---------------------------------------------------------------------------
// Kernel 2 (fused bsort+gather): one block (512 thr) per 64-src bucket.
// Phase A: LDS counting sort of the bucket's pairs + weight pack (stays in
// LDS -- no sorted_pk/nstart/nend HBM round-trip).
// Phase B: segmented reduction over bf16 h straight from the LDS edge list.
// 8 waves, one node per wave in parallel (8 nodes/iter, 64 nodes total).
// ---------------------------------------------------------------------------
__global__ __launch_bounds__(512) void gat_sortgather_kernel(
    const u32* __restrict__ pair, const int* __restrict__ bcur,
    const float* __restrict__ s_src, const float* __restrict__ s_dst,
    const __hip_bfloat16* __restrict__ h_bf, float* __restrict__ out, int N)
{
    __shared__ u32 chunk[BUCKET_CAP];   // 16 KB raw pairs
    __shared__ u32 slds[BUCKET_CAP];    // 16 KB sorted (dst | f16(wgt)<<16)
    __shared__ int cur[64];
    __shared__ int nst[64];
    __shared__ int nen[64];
    __shared__ float ssl[64];

    const int b = blockIdx.x;
    const int t = threadIdx.x;
    const int s0 = b << 6;
    const int abase = b * BUCKET_CAP;
    const int n = min(bcur[b], BUCKET_CAP);

    if (t < 64) {
        cur[t] = 0;
        ssl[t] = (s0 + t < N) ? s_src[s0 + t] : 0.f;
    }
    __syncthreads();
    for (int i = t; i < n; i += 512) {
        const u32 p = pair[abase + i];
        chunk[i] = p;
        atomicAdd(&cur[p >> 16], 1);
    }
    __syncthreads();
    if (t < 64) {   // lanes 0..63 of wave 0: exclusive scan of 64 counts
        const int v = cur[t];
        int incl = v;
#pragma unroll
        for (int off = 1; off < 64; off <<= 1) {
            const int nv = __shfl_up(incl, off);
            if (t >= off) incl += nv;
        }
        const int excl = incl - v;
        nst[t] = excl;
        nen[t] = excl + v;
        cur[t] = excl;
    }
    __syncthreads();
    for (int i = t; i < n; i += 512) {
        const u32 p = chunk[i];
        const int sl = p >> 16;
        const int d = (int)(p & 0xFFFFu);
        const int slot = atomicAdd(&cur[sl], 1);
        const float sc = ssl[sl] + s_dst[d];
        const float lr = sc > 0.f ? sc : ALPHA * sc;
        const float wgt = __expf(-lr);
        const u32 wh = (u32)__half_as_ushort(__float2half(wgt));
        slds[slot] = (u32)d | (wh << 16);
    }
    __syncthreads();

    // ---------------- phase B: gather from LDS edge list ----------------
    const int wv = t >> 6;       // 0..7
    const int lane = t & 63;
    const int q = lane >> 3;     // edge slot 0..7
    const int c = lane & 7;      // feature octet 0..7
    const __bf16* hb = (const __bf16*)h_bf;

    for (int nl = wv; nl < 64; nl += 8) {
        const int node = s0 + nl;
        if (node >= N) break;
        const int start = nst[nl];
        const int end = nen[nl];

        float acc0[8], acc1[8];
#pragma unroll
        for (int j = 0; j < 8; ++j) { acc0[j] = 0.f; acc1[j] = 0.f; }
        float wsum0 = 0.f, wsum1 = 0.f;

        int e = start + q;
        for (; e + 8 < end; e += 16) {
            const u32 p0 = slds[e];
            const u32 p1 = slds[e + 8];
            const int d0 = (int)(p0 & 0xFFFFu);
            const int d1 = (int)(p1 & 0xFFFFu);
            const bf16x8 hv0 = *(const bf16x8*)(hb + (long)d0 * FDIM + 8 * c);
            const bf16x8 hv1 = *(const bf16x8*)(hb + (long)d1 * FDIM + 8 * c);
            const float w0 = __half2float(__ushort_as_half((u16)(p0 >> 16)));
            const float w1 = __half2float(__ushort_as_half((u16)(p1 >> 16)));
#pragma unroll
            for (int j = 0; j < 8; ++j) {
                acc0[j] += w0 * (float)hv0[j];
                acc1[j] += w1 * (float)hv1[j];
            }
            wsum0 += w0;
            wsum1 += w1;
        }
        if (e < end) {
            const u32 p0 = slds[e];
            const int d0 = (int)(p0 & 0xFFFFu);
            const bf16x8 hv0 = *(const bf16x8*)(hb + (long)d0 * FDIM + 8 * c);
            const float w0 = __half2float(__ushort_as_half((u16)(p0 >> 16)));
#pragma unroll
            for (int j = 0; j < 8; ++j) acc0[j] += w0 * (float)hv0[j];
            wsum0 += w0;
        }

        float acc[8];
#pragma unroll
        for (int j = 0; j < 8; ++j) acc[j] = acc0[j] + acc1[j];
        float wsum = wsum0 + wsum1;

#pragma unroll
        for (int off = 8; off < 64; off <<= 1) {
#pragma unroll
            for (int j = 0; j < 8; ++j) acc[j] += __shfl_xor(acc[j], off);
            wsum += __shfl_xor(wsum, off);
        }

        if (q == 0) {
            const float inv = 1.0f / wsum;
            float o[8];
#pragma unroll
            for (int j = 0; j < 8; ++j) {
                const float v = acc[j] * inv;
                o[j] = v > 0.f ? v : expm1f(v);
            }
            float* op = &out[(long)node * FDIM + 8 * c];
            *(float4*)op = make_float4(o[0], o[1], o[2], o[3]);
            *(float4*)(op + 4) = make_float4(o[4], o[5], o[6], o[7]);
        }
    }
}

extern "C" void kernel_launch(void* const* d_in, const int* in_sizes, int n_in,
                              void* d_out, int out_size, void* d_ws, size_t ws_size,
                              hipStream_t stream) {
    const float* x = (const float*)d_in[0];
    const float* W = (const float*)d_in[1];
    const float* a = (const float*)d_in[2];
    const int* ei  = (const int*)d_in[3];

    const int N = in_sizes[0] / KDIM;       // 50000
    const int E = in_sizes[3] / 2;          // 1600000
    const int NBU = (N + 63) >> 6;          // 782 buckets of 64 srcs
    const int NBLK = (E + BIN_CHUNK - 1) / BIN_CHUNK;  // 391 bin chunks
    const int GB = (N + 127) / 128;                    // 391 gemm blocks
    const int* srcA = ei;
    const int* dstA = ei + E;

    // workspace layout (all regions 16B aligned; ~20 MB)
    __hip_bfloat16* h_bf = (__hip_bfloat16*)d_ws;          // N*64 bf16
    __hip_bfloat16* w_t  = h_bf + (size_t)N * FDIM;        // 64*256 bf16
    float* s_src = (float*)(w_t + KDIM * FDIM);            // N
    float* s_dst = s_src + N;                              // N
    int* bcur    = (int*)(s_dst + N);                      // 1024 (zeroed by wt)
    u32* pair    = (u32*)(bcur + 1024);                    // NBU*CAP arena
    float* out   = (float*)d_out;

    gat_wt_kernel<<<dim3((KDIM * FDIM + 255) / 256), dim3(256), 0, stream>>>(
        W, w_t, bcur);

    gat_gemm_bin_kernel<<<dim3(NBLK + GB), dim3(256), 0, stream>>>(
        x, w_t, a, h_bf, s_src, s_dst, srcA, dstA, bcur, pair, N, E, NBU, NBLK);

    gat_sortgather_kernel<<<dim3(NBU), dim3(512), 0, stream>>>(
        pair, bcur, s_src, s_dst, h_bf, out, N);
}